// Round 1
// baseline (2766.529 us; speedup 1.0000x reference)
//
#include <hip/hip_runtime.h>
#include <cstdint>
#include <cstddef>

#define HW 65536
#define HGT 256
#define WID 256
#define CDIM 384
#define C3 1152
#define HEADS 8
#define HD 48
#define NCHUNK 128
#define CHUNK (HW / NCHUNK)  // 512

// ---------------- fp32 SGEMM: C[M,N] = A[M,K] @ B[K,N], all row-major ---------
// BM=BN=128, BK=16, 256 threads, 8x8 micro-tile per thread.
// M,N,K all divisible by tile dims for every call site (1152/384 x 65536 x 384).
__global__ __launch_bounds__(256)
void sgemm128(const float* __restrict__ A, const float* __restrict__ B,
              float* __restrict__ C, int M, int N, int K) {
  constexpr int BM = 128, BN = 128, BK = 16;
  __shared__ float As[BK][BM + 4];  // k-major (transposed on store); +4 pad
  __shared__ float Bs[BK][BN + 4];
  const int t = threadIdx.x;
  const int bm = blockIdx.x, bn = blockIdx.y;
  const int tm = (t >> 4) << 3;  // 16x16 thread grid, 8x8 each
  const int tn = (t & 15) << 3;
  const float* Ab = A + (size_t)bm * BM * K;
  const float* Bb = B + (size_t)bn * BN;
  float acc[8][8];
#pragma unroll
  for (int i = 0; i < 8; i++)
#pragma unroll
    for (int j = 0; j < 8; j++) acc[i][j] = 0.f;

  for (int k0 = 0; k0 < K; k0 += BK) {
    // A tile: 128x16 = 512 float4; transpose into As[k][m]
#pragma unroll
    for (int u = 0; u < 2; u++) {
      int f = t + u * 256;
      int row = f >> 2;
      int kq = f & 3;
      float4 a = *(const float4*)(Ab + (size_t)row * K + k0 + kq * 4);
      As[kq * 4 + 0][row] = a.x;
      As[kq * 4 + 1][row] = a.y;
      As[kq * 4 + 2][row] = a.z;
      As[kq * 4 + 3][row] = a.w;
    }
    // B tile: 16x128 = 512 float4, layout matches
#pragma unroll
    for (int u = 0; u < 2; u++) {
      int f = t + u * 256;
      int row = f >> 5;
      int c = f & 31;
      *(float4*)(&Bs[row][c * 4]) =
          *(const float4*)(Bb + (size_t)(k0 + row) * N + c * 4);
    }
    __syncthreads();
#pragma unroll
    for (int kk = 0; kk < BK; kk++) {
      float a[8], b[8];
#pragma unroll
      for (int i = 0; i < 8; i++) a[i] = As[kk][tm + i];
#pragma unroll
      for (int j = 0; j < 8; j++) b[j] = Bs[kk][tn + j];
#pragma unroll
      for (int i = 0; i < 8; i++)
#pragma unroll
        for (int j = 0; j < 8; j++) acc[i][j] = fmaf(a[i], b[j], acc[i][j]);
    }
    __syncthreads();
  }
  float* Cb = C + (size_t)bm * BM * N + bn * BN;
#pragma unroll
  for (int i = 0; i < 8; i++) {
#pragma unroll
    for (int j = 0; j < 8; j += 4) {
      float4 v = make_float4(acc[i][j], acc[i][j + 1], acc[i][j + 2], acc[i][j + 3]);
      *(float4*)(Cb + (size_t)(tm + i) * N + tn + j) = v;
    }
  }
}

// ---------------- depthwise 3x3, pad 1 (cross-correlation) --------------------
// Block = 256 threads = one 256-px row, 4 output rows per block, one channel.
__global__ __launch_bounds__(256)
void dwconv3x3(const float* __restrict__ in, const float* __restrict__ wgt,
               float* __restrict__ out) {
  const int ch = blockIdx.y;
  const int y0 = blockIdx.x * 4;
  const int t = threadIdx.x;
  __shared__ float rows[6][264];  // cols -1..256 at index x+1; stride 264 (8 mod 32)
  const float* inc = in + (size_t)ch * HW;
  float w9[9];
#pragma unroll
  for (int k = 0; k < 9; k++) w9[k] = wgt[ch * 9 + k];
  if (t < 6) {
    rows[t][0] = 0.f;
    rows[t][WID + 1] = 0.f;
  }
  for (int i = t; i < 6 * WID; i += 256) {
    int r = i >> 8;
    int x = i & 255;
    int y = y0 - 1 + r;
    rows[r][1 + x] = (y >= 0 && y < HGT) ? inc[(size_t)y * WID + x] : 0.f;
  }
  __syncthreads();
  const int x = t;
#pragma unroll
  for (int r = 0; r < 4; r++) {
    float s = 0.f;
#pragma unroll
    for (int ky = 0; ky < 3; ky++)
#pragma unroll
      for (int kx = 0; kx < 3; kx++)
        s = fmaf(w9[ky * 3 + kx], rows[r + ky][x + kx], s);
    out[(size_t)ch * HW + (size_t)(y0 + r) * WID + x] = s;
  }
}

// ---------------- gram matrices + squared norms (split-K partials) ------------
// grid (NCHUNK, HEADS). Per block: partial S[48][48] = q·k^T over its 512-px
// chunk, plus partial sum-of-squares for q and k rows. No atomics (deterministic).
__global__ __launch_bounds__(256)
void gram48(const float* __restrict__ qkvdw, float* __restrict__ Spart,
            float* __restrict__ qpart, float* __restrict__ kpart) {
  const int ck = blockIdx.x;
  const int h = blockIdx.y;
  const int t = threadIdx.x;
  const int ty = t >> 4, tx = t & 15;  // 16x16 threads, 3x3 outputs each
  __shared__ float Qs[HD][33], Ks[HD][33];
  const float* qb = qkvdw + (size_t)(h * HD) * HW + ck * CHUNK;
  const float* kb = qkvdw + (size_t)(CDIM + h * HD) * HW + ck * CHUNK;
  float acc[3][3] = {{0, 0, 0}, {0, 0, 0}, {0, 0, 0}};
  float nacc = 0.f;
  for (int n0 = 0; n0 < CHUNK; n0 += 32) {
    __syncthreads();
    for (int i = t; i < HD * 32; i += 256) {
      int r = i >> 5, c = i & 31;
      Qs[r][c] = qb[(size_t)r * HW + n0 + c];
      Ks[r][c] = kb[(size_t)r * HW + n0 + c];
    }
    __syncthreads();
#pragma unroll 4
    for (int col = 0; col < 32; col++) {
      float qv[3], kv[3];
#pragma unroll
      for (int i = 0; i < 3; i++) qv[i] = Qs[ty * 3 + i][col];
#pragma unroll
      for (int j = 0; j < 3; j++) kv[j] = Ks[tx * 3 + j][col];
#pragma unroll
      for (int i = 0; i < 3; i++)
#pragma unroll
        for (int j = 0; j < 3; j++) acc[i][j] = fmaf(qv[i], kv[j], acc[i][j]);
    }
    if (t < HD) {
#pragma unroll 4
      for (int col = 0; col < 32; col++) nacc = fmaf(Qs[t][col], Qs[t][col], nacc);
    } else if (t >= 64 && t < 64 + HD) {
      int r = t - 64;
#pragma unroll 4
      for (int col = 0; col < 32; col++) nacc = fmaf(Ks[r][col], Ks[r][col], nacc);
    }
  }
  float* Sp = Spart + ((size_t)ck * HEADS + h) * HD * HD;
#pragma unroll
  for (int i = 0; i < 3; i++)
#pragma unroll
    for (int j = 0; j < 3; j++)
      Sp[(ty * 3 + i) * HD + tx * 3 + j] = acc[i][j];
  if (t < HD)
    qpart[((size_t)ck * HEADS + h) * HD + t] = nacc;
  else if (t >= 64 && t < 64 + HD)
    kpart[((size_t)ck * HEADS + h) * HD + (t - 64)] = nacc;
}

// ---------------- reduce partials + temperature + softmax ---------------------
// grid HEADS, block 64 (thread c<48 owns attn row c).
__global__ __launch_bounds__(64)
void attn_softmax(const float* __restrict__ Spart, const float* __restrict__ qpart,
                  const float* __restrict__ kpart, const float* __restrict__ log_temp,
                  float* __restrict__ attn) {
  const int h = blockIdx.x;
  const int c = threadIdx.x;
  __shared__ float kns[HD];
  const int cc = (c < HD) ? c : 0;
  float qs = 0.f, ks = 0.f;
  for (int ck = 0; ck < NCHUNK; ck++) {
    qs += qpart[((size_t)ck * HEADS + h) * HD + cc];
    ks += kpart[((size_t)ck * HEADS + h) * HD + cc];
  }
  float qn = fmaxf(sqrtf(qs), 1e-12f);
  if (c < HD) kns[c] = fmaxf(sqrtf(ks), 1e-12f);
  __syncthreads();
  if (c >= HD) return;
  float lt = log_temp[h];
  float temp = (lt > 20.f ? lt : log1pf(expf(lt))) + 1e-6f;  // softplus + eps
  float lg[HD];
#pragma unroll
  for (int d = 0; d < HD; d++) lg[d] = 0.f;
  for (int ck = 0; ck < NCHUNK; ck++) {
    const float* Sp = Spart + (((size_t)ck * HEADS + h) * HD + c) * HD;
#pragma unroll
    for (int d = 0; d < HD; d++) lg[d] += Sp[d];
  }
  float mx = -1e30f;
#pragma unroll
  for (int d = 0; d < HD; d++) {
    lg[d] = lg[d] / (qn * kns[d]) * temp;
    mx = fmaxf(mx, lg[d]);
  }
  float sum = 0.f;
#pragma unroll
  for (int d = 0; d < HD; d++) {
    lg[d] = expf(lg[d] - mx);
    sum += lg[d];
  }
  float inv = 1.f / sum;
#pragma unroll
  for (int d = 0; d < HD; d++) attn[((size_t)h * HD + c) * HD + d] = lg[d] * inv;
}

// ---------------- fold proj_w through block-diagonal attn ---------------------
// M[o, h*48+d] = sum_c proj_w[o, h*48+c] * attn[h,c,d]   (384x384, K=48)
__global__ __launch_bounds__(256)
void fuse_proj(const float* __restrict__ proj_w, const float* __restrict__ attn,
               float* __restrict__ Mmat) {
  int idx = blockIdx.x * 256 + threadIdx.x;
  int o = idx / CDIM, j = idx % CDIM;
  int h = j / HD, d = j % HD;
  float s = 0.f;
#pragma unroll 8
  for (int c = 0; c < HD; c++)
    s = fmaf(proj_w[(size_t)o * CDIM + h * HD + c],
             attn[((size_t)h * HD + c) * HD + d], s);
  Mmat[idx] = s;
}

extern "C" void kernel_launch(void* const* d_in, const int* in_sizes, int n_in,
                              void* d_out, int out_size, void* d_ws, size_t ws_size,
                              hipStream_t stream) {
  const float* x = (const float*)d_in[0];       // (2, 384, 256, 256)
  const float* qkv_w = (const float*)d_in[1];   // (1152, 384)
  const float* dw_w = (const float*)d_in[2];    // (1152, 1, 3, 3)
  const float* proj_w = (const float*)d_in[3];  // (384, 384)
  const float* log_t = (const float*)d_in[4];   // (8,)
  float* out = (float*)d_out;

  float* ws = (float*)d_ws;
  float* qkv = ws;                                           // C3*HW
  float* qkvdw = qkv + (size_t)C3 * HW;                      // C3*HW
  float* Spart = qkvdw + (size_t)C3 * HW;                    // NCHUNK*HEADS*HD*HD
  float* qpart = Spart + (size_t)NCHUNK * HEADS * HD * HD;   // NCHUNK*HEADS*HD
  float* kpart = qpart + (size_t)NCHUNK * HEADS * HD;        // NCHUNK*HEADS*HD
  float* attn = kpart + (size_t)NCHUNK * HEADS * HD;         // HEADS*HD*HD
  float* Mmat = attn + (size_t)HEADS * HD * HD;              // CDIM*CDIM

  for (int b = 0; b < 2; b++) {
    const float* xb = x + (size_t)b * CDIM * HW;
    float* outb = out + (size_t)b * CDIM * HW;
    // 1) qkv = qkv_w @ x   (1152 x 65536)
    sgemm128<<<dim3(C3 / 128, HW / 128), 256, 0, stream>>>(qkv_w, xb, qkv, C3, HW, CDIM);
    // 2) depthwise 3x3
    dwconv3x3<<<dim3(HGT / 4, C3), 256, 0, stream>>>(qkv, dw_w, qkvdw);
    // 3) gram matrices + norms (split-K partials)
    gram48<<<dim3(NCHUNK, HEADS), 256, 0, stream>>>(qkvdw, Spart, qpart, kpart);
    // 4) reduce + scale + softmax -> attn (8 x 48 x 48)
    attn_softmax<<<dim3(HEADS), 64, 0, stream>>>(Spart, qpart, kpart, log_t, attn);
    // 5) fold proj through attn -> Mmat (384 x 384)
    fuse_proj<<<dim3(CDIM * CDIM / 256), 256, 0, stream>>>(proj_w, attn, Mmat);
    // 6) out = Mmat @ v   (384 x 65536)
    sgemm128<<<dim3(CDIM / 128, HW / 128), 256, 0, stream>>>(
        Mmat, qkvdw + (size_t)2 * CDIM * HW, outb, CDIM, HW, CDIM);
  }
}

// Round 4
// 1915.011 us; speedup vs baseline: 1.4447x; 1.4447x over previous
//
#include <hip/hip_runtime.h>
#include <cstdint>
#include <cstddef>

#define HW 65536
#define HGT 256
#define WID 256
#define CDIM 384
#define C3 1152
#define HEADS 8
#define HD 48
#define NCHUNK 128
#define CHUNK (HW / NCHUNK)  // 512

typedef unsigned short u16;
typedef __attribute__((ext_vector_type(8))) short short8;   // 8 bf16 (4 VGPRs)
typedef __attribute__((ext_vector_type(4))) float f32x4;    // MFMA C/D
typedef __attribute__((ext_vector_type(4))) u16 us4;

__device__ __forceinline__ u16 f2bf_rn(float f) {
  uint32_t u = __float_as_uint(f);
  return (u16)((u + 0x7FFFu + ((u >> 16) & 1u)) >> 16);
}
__device__ __forceinline__ float bf2f(u16 s) {
  return __uint_as_float((uint32_t)s << 16);
}

// async global->LDS, 16B/lane; LDS dest = wave-uniform base + lane*16 (HW rule)
__device__ __forceinline__ void stage16(const void* g, void* lds_wave_base) {
  __builtin_amdgcn_global_load_lds(
      (const __attribute__((address_space(1))) void*)g,
      (__attribute__((address_space(3))) void*)lds_wave_base, 16, 0, 0);
}

// ------------- split-bf16 MFMA GEMM: C[M,N]fp32 = (Ah+Al)[M,K] @ (Bh+Bl)^T ----
// A row-major [M][K] bf16; B given TRANSPOSED: [N][K] bf16. K % 32 == 0.
// Tile 128x128, BK=32, 256 thr = 4 waves (2x2), wave tile 64x64 (4x4 16x16 frags).
// LDS: 4 linear 8KB buffers (Ah,Al,Bh,Bl); chunk-XOR swizzle (row>>1)&3 applied
// on the GLOBAL source and on the ds_read address (both sides, LDS stays linear).
__global__ __launch_bounds__(256)
void mfma_gemm_split(const u16* __restrict__ Ah, const u16* __restrict__ Al,
                     const u16* __restrict__ Bh, const u16* __restrict__ Bl,
                     float* __restrict__ C, int N, int K) {
  __shared__ u16 sm[4][4096];  // [0]=Ah [1]=Al [2]=Bh [3]=Bl ; slot=(row, chunk)
  const int t = threadIdx.x;
  const int wid = t >> 6, lane = t & 63;
  const int m0 = blockIdx.x * 128, n0 = blockIdx.y * 128;
  const int wm = (wid >> 1) * 64, wn = (wid & 1) * 64;

  f32x4 acc[4][4];
#pragma unroll
  for (int i = 0; i < 4; i++)
#pragma unroll
    for (int j = 0; j < 4; j++) acc[i][j] = {0.f, 0.f, 0.f, 0.f};

  for (int k0 = 0; k0 < K; k0 += 32) {
    // ---- stage: 512 slots/buffer; wave stages 64-slot runs (linear LDS dest)
#pragma unroll
    for (int u = 0; u < 2; u++) {
      const int s = u * 256 + wid * 64 + lane;
      const int row = s >> 2;
      const int cd = (s & 3) ^ ((row >> 1) & 3);     // pre-swizzled global chunk
      const size_t offA = (size_t)(m0 + row) * K + k0 + cd * 8;
      const size_t offB = (size_t)(n0 + row) * K + k0 + cd * 8;
      const int lb = (u * 256 + wid * 64) * 8;       // ushort offset of wave base
      stage16(Ah + offA, &sm[0][lb]);
      stage16(Al + offA, &sm[1][lb]);
      stage16(Bh + offB, &sm[2][lb]);
      stage16(Bl + offB, &sm[3][lb]);
    }
    __syncthreads();  // compiler drains vmcnt(0) before barrier

    short8 ah[4], al[4], bh[4], bl[4];
#pragma unroll
    for (int f = 0; f < 4; f++) {
      const int ra = wm + f * 16 + (lane & 15);
      const int oa = ra * 32 + ((((lane >> 4) ^ ((ra >> 1) & 3))) << 3);
      ah[f] = *(const short8*)&sm[0][oa];
      al[f] = *(const short8*)&sm[1][oa];
      const int rb = wn + f * 16 + (lane & 15);
      const int ob = rb * 32 + ((((lane >> 4) ^ ((rb >> 1) & 3))) << 3);
      bh[f] = *(const short8*)&sm[2][ob];
      bl[f] = *(const short8*)&sm[3][ob];
    }
#pragma unroll
    for (int i = 0; i < 4; i++)
#pragma unroll
      for (int j = 0; j < 4; j++) {
        acc[i][j] = __builtin_amdgcn_mfma_f32_16x16x32_bf16(ah[i], bh[j], acc[i][j], 0, 0, 0);
        acc[i][j] = __builtin_amdgcn_mfma_f32_16x16x32_bf16(ah[i], bl[j], acc[i][j], 0, 0, 0);
        acc[i][j] = __builtin_amdgcn_mfma_f32_16x16x32_bf16(al[i], bh[j], acc[i][j], 0, 0, 0);
      }
    __syncthreads();
  }
  // epilogue: C/D layout col=lane&15, row=(lane>>4)*4+reg  [m89-verified]
  float* Cb = C + (size_t)(m0 + wm) * N + n0 + wn;
#pragma unroll
  for (int i = 0; i < 4; i++) {
    const int r0 = i * 16 + ((lane >> 4) << 2);
#pragma unroll
    for (int j = 0; j < 4; j++) {
      const int cc = j * 16 + (lane & 15);
#pragma unroll
      for (int r = 0; r < 4; r++) Cb[(size_t)(r0 + r) * N + cc] = acc[i][j][r];
    }
  }
}

// ------------- transpose + split-convert: in[384][HW] f32 -> out[HW][384] bf16 --
__global__ __launch_bounds__(256)
void transpose_cvt(const float* __restrict__ in, u16* __restrict__ hi,
                   u16* __restrict__ lo) {
  __shared__ float tbuf[64][65];
  const int n0 = blockIdx.x * 64, c0 = blockIdx.y * 64;
  const int tx = threadIdx.x & 63, ty = threadIdx.x >> 6;
#pragma unroll
  for (int c = ty; c < 64; c += 4)
    tbuf[tx][c] = in[(size_t)(c0 + c) * HW + n0 + tx];
  __syncthreads();
  const int cq = (threadIdx.x & 15) << 2;
  const int nb = threadIdx.x >> 4;
#pragma unroll
  for (int p = 0; p < 4; p++) {
    const int n = p * 16 + nb;
    us4 h, l;
#pragma unroll
    for (int i = 0; i < 4; i++) {
      float f = tbuf[n][cq + i];
      u16 hb = f2bf_rn(f);
      h[i] = hb;
      l[i] = f2bf_rn(f - bf2f(hb));
    }
    *(us4*)&hi[(size_t)(n0 + n) * CDIM + c0 + cq] = h;
    *(us4*)&lo[(size_t)(n0 + n) * CDIM + c0 + cq] = l;
  }
}

// ------------- elementwise split-convert (weights / Mmat) ---------------------
__global__ __launch_bounds__(256)
void split_cvt(const float* __restrict__ in, u16* __restrict__ hi,
               u16* __restrict__ lo, int n) {
  int i = blockIdx.x * 256 + threadIdx.x;
  if (i < n) {
    float f = in[i];
    u16 hb = f2bf_rn(f);
    hi[i] = hb;
    lo[i] = f2bf_rn(f - bf2f(hb));
  }
}

// ---------------- depthwise 3x3, pad 1 (cross-correlation) --------------------
__global__ __launch_bounds__(256)
void dwconv3x3(const float* __restrict__ in, const float* __restrict__ wgt,
               float* __restrict__ out) {
  const int ch = blockIdx.y;
  const int y0 = blockIdx.x * 4;
  const int t = threadIdx.x;
  __shared__ float rows[6][264];
  const float* inc = in + (size_t)ch * HW;
  float w9[9];
#pragma unroll
  for (int k = 0; k < 9; k++) w9[k] = wgt[ch * 9 + k];
  if (t < 6) {
    rows[t][0] = 0.f;
    rows[t][WID + 1] = 0.f;
  }
  for (int i = t; i < 6 * WID; i += 256) {
    int r = i >> 8;
    int x = i & 255;
    int y = y0 - 1 + r;
    rows[r][1 + x] = (y >= 0 && y < HGT) ? inc[(size_t)y * WID + x] : 0.f;
  }
  __syncthreads();
  const int x = t;
#pragma unroll
  for (int r = 0; r < 4; r++) {
    float s = 0.f;
#pragma unroll
    for (int ky = 0; ky < 3; ky++)
#pragma unroll
      for (int kx = 0; kx < 3; kx++)
        s = fmaf(w9[ky * 3 + kx], rows[r + ky][x + kx], s);
    out[(size_t)ch * HW + (size_t)(y0 + r) * WID + x] = s;
  }
}

// ---------------- gram matrices + squared norms (split-K partials) ------------
__global__ __launch_bounds__(256)
void gram48(const float* __restrict__ qkvdw, float* __restrict__ Spart,
            float* __restrict__ qpart, float* __restrict__ kpart) {
  const int ck = blockIdx.x;
  const int h = blockIdx.y;
  const int t = threadIdx.x;
  const int ty = t >> 4, tx = t & 15;
  __shared__ float Qs[HD][33], Ks[HD][33];
  const float* qb = qkvdw + (size_t)(h * HD) * HW + ck * CHUNK;
  const float* kb = qkvdw + (size_t)(CDIM + h * HD) * HW + ck * CHUNK;
  float acc[3][3] = {{0, 0, 0}, {0, 0, 0}, {0, 0, 0}};
  float nacc = 0.f;
  for (int n0 = 0; n0 < CHUNK; n0 += 32) {
    __syncthreads();
    for (int i = t; i < HD * 32; i += 256) {
      int r = i >> 5, c = i & 31;
      Qs[r][c] = qb[(size_t)r * HW + n0 + c];
      Ks[r][c] = kb[(size_t)r * HW + n0 + c];
    }
    __syncthreads();
#pragma unroll 4
    for (int col = 0; col < 32; col++) {
      float qv[3], kv[3];
#pragma unroll
      for (int i = 0; i < 3; i++) qv[i] = Qs[ty * 3 + i][col];
#pragma unroll
      for (int j = 0; j < 3; j++) kv[j] = Ks[tx * 3 + j][col];
#pragma unroll
      for (int i = 0; i < 3; i++)
#pragma unroll
        for (int j = 0; j < 3; j++) acc[i][j] = fmaf(qv[i], kv[j], acc[i][j]);
    }
    if (t < HD) {
#pragma unroll 4
      for (int col = 0; col < 32; col++) nacc = fmaf(Qs[t][col], Qs[t][col], nacc);
    } else if (t >= 64 && t < 64 + HD) {
      int r = t - 64;
#pragma unroll 4
      for (int col = 0; col < 32; col++) nacc = fmaf(Ks[r][col], Ks[r][col], nacc);
    }
  }
  float* Sp = Spart + ((size_t)ck * HEADS + h) * HD * HD;
#pragma unroll
  for (int i = 0; i < 3; i++)
#pragma unroll
    for (int j = 0; j < 3; j++)
      Sp[(ty * 3 + i) * HD + tx * 3 + j] = acc[i][j];
  if (t < HD)
    qpart[((size_t)ck * HEADS + h) * HD + t] = nacc;
  else if (t >= 64 && t < 64 + HD)
    kpart[((size_t)ck * HEADS + h) * HD + (t - 64)] = nacc;
}

// ---------------- reduce partials + temperature + softmax ---------------------
__global__ __launch_bounds__(64)
void attn_softmax(const float* __restrict__ Spart, const float* __restrict__ qpart,
                  const float* __restrict__ kpart, const float* __restrict__ log_temp,
                  float* __restrict__ attn) {
  const int h = blockIdx.x;
  const int c = threadIdx.x;
  __shared__ float kns[HD];
  const int cc = (c < HD) ? c : 0;
  float qs = 0.f, ks = 0.f;
  for (int ck = 0; ck < NCHUNK; ck++) {
    qs += qpart[((size_t)ck * HEADS + h) * HD + cc];
    ks += kpart[((size_t)ck * HEADS + h) * HD + cc];
  }
  float qn = fmaxf(sqrtf(qs), 1e-12f);
  if (c < HD) kns[c] = fmaxf(sqrtf(ks), 1e-12f);
  __syncthreads();
  if (c >= HD) return;
  float lt = log_temp[h];
  float temp = (lt > 20.f ? lt : log1pf(expf(lt))) + 1e-6f;
  float lg[HD];
#pragma unroll
  for (int d = 0; d < HD; d++) lg[d] = 0.f;
  for (int ck = 0; ck < NCHUNK; ck++) {
    const float* Sp = Spart + (((size_t)ck * HEADS + h) * HD + c) * HD;
#pragma unroll
    for (int d = 0; d < HD; d++) lg[d] += Sp[d];
  }
  float mx = -1e30f;
#pragma unroll
  for (int d = 0; d < HD; d++) {
    lg[d] = lg[d] / (qn * kns[d]) * temp;
    mx = fmaxf(mx, lg[d]);
  }
  float sum = 0.f;
#pragma unroll
  for (int d = 0; d < HD; d++) {
    lg[d] = expf(lg[d] - mx);
    sum += lg[d];
  }
  float inv = 1.f / sum;
#pragma unroll
  for (int d = 0; d < HD; d++) attn[((size_t)h * HD + c) * HD + d] = lg[d] * inv;
}

// ---------------- fold proj_w through block-diagonal attn ---------------------
__global__ __launch_bounds__(256)
void fuse_proj(const float* __restrict__ proj_w, const float* __restrict__ attn,
               float* __restrict__ Mmat) {
  int idx = blockIdx.x * 256 + threadIdx.x;
  int o = idx / CDIM, j = idx % CDIM;
  int h = j / HD, d = j % HD;
  float s = 0.f;
#pragma unroll 8
  for (int c = 0; c < HD; c++)
    s = fmaf(proj_w[(size_t)o * CDIM + h * HD + c],
             attn[((size_t)h * HD + c) * HD + d], s);
  Mmat[idx] = s;
}

extern "C" void kernel_launch(void* const* d_in, const int* in_sizes, int n_in,
                              void* d_out, int out_size, void* d_ws, size_t ws_size,
                              hipStream_t stream) {
  const float* x = (const float*)d_in[0];       // (2, 384, 256, 256)
  const float* qkv_w = (const float*)d_in[1];   // (1152, 384)
  const float* dw_w = (const float*)d_in[2];    // (1152, 1, 3, 3)
  const float* proj_w = (const float*)d_in[3];  // (384, 384)
  const float* log_t = (const float*)d_in[4];   // (8,)
  float* out = (float*)d_out;

  float* ws = (float*)d_ws;
  const size_t C3HW = (size_t)C3 * HW;
  float* qkv = ws;                                          // 302 MB
  float* qkvdw = qkv + C3HW;                                // 302 MB
  float* Spart = qkvdw + C3HW;                              // 9.4 MB
  float* qpart = Spart + (size_t)NCHUNK * HEADS * HD * HD;
  float* kpart = qpart + (size_t)NCHUNK * HEADS * HD;
  float* attn = kpart + (size_t)NCHUNK * HEADS * HD;
  float* Mmat = attn + (size_t)HEADS * HD * HD;
  u16* qkvw_h = (u16*)(Mmat + (size_t)CDIM * CDIM);         // +1.77 MB (persistent)
  u16* qkvw_l = qkvw_h + (size_t)C3 * CDIM;
  // Mh/Ml alias the head of Spart: Spart is dead after attn_softmax; Mh/Ml live
  // only fuse_proj+split_cvt -> epilogue GEMM; next Spart write is the NEXT
  // batch's gram48, strictly after the epilogue GEMM. Lifetimes disjoint.
  u16* Mh = (u16*)Spart;
  u16* Ml = Mh + (size_t)CDIM * CDIM;
  // aliases into the two big buffers (lifetimes disjoint):
  u16* xT_h = (u16*)qkvdw;                                  // dead after GEMM1
  u16* xT_l = xT_h + (size_t)HW * CDIM;
  u16* vT_h = (u16*)qkv;                                    // qkv dead after dwconv
  u16* vT_l = vT_h + (size_t)HW * CDIM;

  split_cvt<<<dim3((C3 * CDIM + 255) / 256), 256, 0, stream>>>(qkv_w, qkvw_h, qkvw_l,
                                                               C3 * CDIM);
  for (int b = 0; b < 2; b++) {
    const float* xb = x + (size_t)b * CDIM * HW;
    float* outb = out + (size_t)b * CDIM * HW;
    // 1) xT (bf16 hi/lo, [n][c]) into qkvdw region
    transpose_cvt<<<dim3(HW / 64, CDIM / 64), 256, 0, stream>>>(xb, xT_h, xT_l);
    // 2) qkv = qkv_w @ x  via MFMA
    mfma_gemm_split<<<dim3(C3 / 128, HW / 128), 256, 0, stream>>>(
        qkvw_h, qkvw_l, xT_h, xT_l, qkv, HW, CDIM);
    // 3) depthwise 3x3 (overwrites xT region — xT is dead)
    dwconv3x3<<<dim3(HGT / 4, C3), 256, 0, stream>>>(qkv, dw_w, qkvdw);
    // 4) gram + norms, 5) softmax, 6) proj fold + split
    gram48<<<dim3(NCHUNK, HEADS), 256, 0, stream>>>(qkvdw, Spart, qpart, kpart);
    attn_softmax<<<dim3(HEADS), 64, 0, stream>>>(Spart, qpart, kpart, log_t, attn);
    fuse_proj<<<dim3(CDIM * CDIM / 256), 256, 0, stream>>>(proj_w, attn, Mmat);
    split_cvt<<<dim3(CDIM * CDIM / 256), 256, 0, stream>>>(Mmat, Mh, Ml, CDIM * CDIM);
    // 7) vT (bf16 hi/lo) into qkv region (qkv dead after dwconv)
    transpose_cvt<<<dim3(HW / 64, CDIM / 64), 256, 0, stream>>>(
        qkvdw + (size_t)2 * CDIM * HW, vT_h, vT_l);
    // 8) out = Mmat @ v via MFMA
    mfma_gemm_split<<<dim3(CDIM / 128, HW / 128), 256, 0, stream>>>(
        Mh, Ml, vT_h, vT_l, outb, HW, CDIM);
  }
}

// Round 10
// 1779.294 us; speedup vs baseline: 1.5548x; 1.0763x over previous
//
#include <hip/hip_runtime.h>
#include <cstdint>
#include <cstddef>

#define HW 65536
#define HGT 256
#define WID 256
#define CDIM 384
#define C3 1152
#define HEADS 8
#define HD 48
#define NCHUNK 128
#define CHUNK (HW / NCHUNK)  // 512

typedef unsigned short u16;
typedef __attribute__((ext_vector_type(8))) short short8;   // 8 bf16 (4 VGPRs)
typedef __attribute__((ext_vector_type(4))) float f32x4;    // MFMA C/D
typedef __attribute__((ext_vector_type(4))) u16 us4;

__device__ __forceinline__ u16 f2bf_rn(float f) {
  uint32_t u = __float_as_uint(f);
  return (u16)((u + 0x7FFFu + ((u >> 16) & 1u)) >> 16);
}
__device__ __forceinline__ float bf2f(u16 s) {
  return __uint_as_float((uint32_t)s << 16);
}

// async global->LDS, 16B/lane; LDS dest = wave-uniform base + lane*16 (HW rule)
__device__ __forceinline__ void stage16(const void* g, void* lds_wave_base) {
  __builtin_amdgcn_global_load_lds(
      (const __attribute__((address_space(1))) void*)g,
      (__attribute__((address_space(3))) void*)lds_wave_base, 16, 0, 0);
}

// ------------- split-bf16 MFMA GEMM: C[M,N]fp32 = (Ah+Al)[M,K] @ (Bh+Bl)^T ----
// A row-major [M][K] bf16; B given TRANSPOSED: [N][K] bf16. K % 32 == 0.
// Tile 128x128, BK=32, 256 thr = 4 waves (2x2), wave tile 64x64 (4x4 16x16 frags).
// 1-D grid with XCD-locality swizzle: all m_tiles blocks sharing one B n-panel
// land on the SAME XCD in consecutive slots (round-4 counters showed 7.3x
// B-panel re-fetch from cross-XCD L2 non-coherence: FETCH 740MB vs 103MB ideal).
// Requires n_tiles % 8 == 0 (512 at both call sites).
__global__ __launch_bounds__(256)
void mfma_gemm_split(const u16* __restrict__ Ah, const u16* __restrict__ Al,
                     const u16* __restrict__ Bh, const u16* __restrict__ Bl,
                     float* __restrict__ C, int N, int K, int m_tiles) {
  __shared__ u16 sm[4][4096];  // [0]=Ah [1]=Al [2]=Bh [3]=Bl ; slot=(row, chunk)
  const int t = threadIdx.x;
  const int wid = t >> 6, lane = t & 63;
  // XCD swizzle decode (bijective: gridDim.x = 8 * per_xcd; per_xcd = npx*m_tiles)
  const int w = blockIdx.x;
  const int xcd = w & 7;
  const int slot = w >> 3;
  const int npx = (int)(gridDim.x >> 3) / m_tiles;  // n-panels per XCD
  const int m0 = (slot % m_tiles) * 128;
  const int n0 = (xcd * npx + slot / m_tiles) * 128;
  const int wm = (wid >> 1) * 64, wn = (wid & 1) * 64;

  f32x4 acc[4][4];
#pragma unroll
  for (int i = 0; i < 4; i++)
#pragma unroll
    for (int j = 0; j < 4; j++) acc[i][j] = {0.f, 0.f, 0.f, 0.f};

  for (int k0 = 0; k0 < K; k0 += 32) {
    // ---- stage: 512 slots/buffer; wave stages 64-slot runs (linear LDS dest)
#pragma unroll
    for (int u = 0; u < 2; u++) {
      const int s = u * 256 + wid * 64 + lane;
      const int row = s >> 2;
      const int cd = (s & 3) ^ ((row >> 1) & 3);     // pre-swizzled global chunk
      const size_t offA = (size_t)(m0 + row) * K + k0 + cd * 8;
      const size_t offB = (size_t)(n0 + row) * K + k0 + cd * 8;
      const int lb = (u * 256 + wid * 64) * 8;       // ushort offset of wave base
      stage16(Ah + offA, &sm[0][lb]);
      stage16(Al + offA, &sm[1][lb]);
      stage16(Bh + offB, &sm[2][lb]);
      stage16(Bl + offB, &sm[3][lb]);
    }
    __syncthreads();  // compiler drains vmcnt(0) before barrier

    short8 ah[4], al[4], bh[4], bl[4];
#pragma unroll
    for (int f = 0; f < 4; f++) {
      const int ra = wm + f * 16 + (lane & 15);
      const int oa = ra * 32 + ((((lane >> 4) ^ ((ra >> 1) & 3))) << 3);
      ah[f] = *(const short8*)&sm[0][oa];
      al[f] = *(const short8*)&sm[1][oa];
      const int rb = wn + f * 16 + (lane & 15);
      const int ob = rb * 32 + ((((lane >> 4) ^ ((rb >> 1) & 3))) << 3);
      bh[f] = *(const short8*)&sm[2][ob];
      bl[f] = *(const short8*)&sm[3][ob];
    }
#pragma unroll
    for (int i = 0; i < 4; i++)
#pragma unroll
      for (int j = 0; j < 4; j++) {
        acc[i][j] = __builtin_amdgcn_mfma_f32_16x16x32_bf16(ah[i], bh[j], acc[i][j], 0, 0, 0);
        acc[i][j] = __builtin_amdgcn_mfma_f32_16x16x32_bf16(ah[i], bl[j], acc[i][j], 0, 0, 0);
        acc[i][j] = __builtin_amdgcn_mfma_f32_16x16x32_bf16(al[i], bh[j], acc[i][j], 0, 0, 0);
      }
    __syncthreads();
  }
  // epilogue: C/D layout col=lane&15, row=(lane>>4)*4+reg  [m89-verified]
  float* Cb = C + (size_t)(m0 + wm) * N + n0 + wn;
#pragma unroll
  for (int i = 0; i < 4; i++) {
    const int r0 = i * 16 + ((lane >> 4) << 2);
#pragma unroll
    for (int j = 0; j < 4; j++) {
      const int cc = j * 16 + (lane & 15);
#pragma unroll
      for (int r = 0; r < 4; r++) Cb[(size_t)(r0 + r) * N + cc] = acc[i][j][r];
    }
  }
}

// ------------- transpose + split-convert: in[384][HW] f32 -> out[HW][384] bf16 --
__global__ __launch_bounds__(256)
void transpose_cvt(const float* __restrict__ in, u16* __restrict__ hi,
                   u16* __restrict__ lo) {
  __shared__ float tbuf[64][65];
  const int n0 = blockIdx.x * 64, c0 = blockIdx.y * 64;
  const int tx = threadIdx.x & 63, ty = threadIdx.x >> 6;
#pragma unroll
  for (int c = ty; c < 64; c += 4)
    tbuf[tx][c] = in[(size_t)(c0 + c) * HW + n0 + tx];
  __syncthreads();
  const int cq = (threadIdx.x & 15) << 2;
  const int nb = threadIdx.x >> 4;
#pragma unroll
  for (int p = 0; p < 4; p++) {
    const int n = p * 16 + nb;
    us4 h, l;
#pragma unroll
    for (int i = 0; i < 4; i++) {
      float f = tbuf[n][cq + i];
      u16 hb = f2bf_rn(f);
      h[i] = hb;
      l[i] = f2bf_rn(f - bf2f(hb));
    }
    *(us4*)&hi[(size_t)(n0 + n) * CDIM + c0 + cq] = h;
    *(us4*)&lo[(size_t)(n0 + n) * CDIM + c0 + cq] = l;
  }
}

// ------------- elementwise split-convert (weights / Mmat) ---------------------
__global__ __launch_bounds__(256)
void split_cvt(const float* __restrict__ in, u16* __restrict__ hi,
               u16* __restrict__ lo, int n) {
  int i = blockIdx.x * 256 + threadIdx.x;
  if (i < n) {
    float f = in[i];
    u16 hb = f2bf_rn(f);
    hi[i] = hb;
    lo[i] = f2bf_rn(f - bf2f(hb));
  }
}

// ---------------- depthwise 3x3, pad 1 (cross-correlation) --------------------
__global__ __launch_bounds__(256)
void dwconv3x3(const float* __restrict__ in, const float* __restrict__ wgt,
               float* __restrict__ out) {
  const int ch = blockIdx.y;
  const int y0 = blockIdx.x * 4;
  const int t = threadIdx.x;
  __shared__ float rows[6][264];
  const float* inc = in + (size_t)ch * HW;
  float w9[9];
#pragma unroll
  for (int k = 0; k < 9; k++) w9[k] = wgt[ch * 9 + k];
  if (t < 6) {
    rows[t][0] = 0.f;
    rows[t][WID + 1] = 0.f;
  }
  for (int i = t; i < 6 * WID; i += 256) {
    int r = i >> 8;
    int x = i & 255;
    int y = y0 - 1 + r;
    rows[r][1 + x] = (y >= 0 && y < HGT) ? inc[(size_t)y * WID + x] : 0.f;
  }
  __syncthreads();
  const int x = t;
#pragma unroll
  for (int r = 0; r < 4; r++) {
    float s = 0.f;
#pragma unroll
    for (int ky = 0; ky < 3; ky++)
#pragma unroll
      for (int kx = 0; kx < 3; kx++)
        s = fmaf(w9[ky * 3 + kx], rows[r + ky][x + kx], s);
    out[(size_t)ch * HW + (size_t)(y0 + r) * WID + x] = s;
  }
}

// ---------------- gram matrices + squared norms (split-K partials) ------------
__global__ __launch_bounds__(256)
void gram48(const float* __restrict__ qkvdw, float* __restrict__ Spart,
            float* __restrict__ qpart, float* __restrict__ kpart) {
  const int ck = blockIdx.x;
  const int h = blockIdx.y;
  const int t = threadIdx.x;
  const int ty = t >> 4, tx = t & 15;
  __shared__ float Qs[HD][33], Ks[HD][33];
  const float* qb = qkvdw + (size_t)(h * HD) * HW + ck * CHUNK;
  const float* kb = qkvdw + (size_t)(CDIM + h * HD) * HW + ck * CHUNK;
  float acc[3][3] = {{0, 0, 0}, {0, 0, 0}, {0, 0, 0}};
  float nacc = 0.f;
  for (int n0 = 0; n0 < CHUNK; n0 += 32) {
    __syncthreads();
    for (int i = t; i < HD * 32; i += 256) {
      int r = i >> 5, c = i & 31;
      Qs[r][c] = qb[(size_t)r * HW + n0 + c];
      Ks[r][c] = kb[(size_t)r * HW + n0 + c];
    }
    __syncthreads();
#pragma unroll 4
    for (int col = 0; col < 32; col++) {
      float qv[3], kv[3];
#pragma unroll
      for (int i = 0; i < 3; i++) qv[i] = Qs[ty * 3 + i][col];
#pragma unroll
      for (int j = 0; j < 3; j++) kv[j] = Ks[tx * 3 + j][col];
#pragma unroll
      for (int i = 0; i < 3; i++)
#pragma unroll
        for (int j = 0; j < 3; j++) acc[i][j] = fmaf(qv[i], kv[j], acc[i][j]);
    }
    if (t < HD) {
#pragma unroll 4
      for (int col = 0; col < 32; col++) nacc = fmaf(Qs[t][col], Qs[t][col], nacc);
    } else if (t >= 64 && t < 64 + HD) {
      int r = t - 64;
#pragma unroll 4
      for (int col = 0; col < 32; col++) nacc = fmaf(Ks[r][col], Ks[r][col], nacc);
    }
  }
  float* Sp = Spart + ((size_t)ck * HEADS + h) * HD * HD;
#pragma unroll
  for (int i = 0; i < 3; i++)
#pragma unroll
    for (int j = 0; j < 3; j++)
      Sp[(ty * 3 + i) * HD + tx * 3 + j] = acc[i][j];
  if (t < HD)
    qpart[((size_t)ck * HEADS + h) * HD + t] = nacc;
  else if (t >= 64 && t < 64 + HD)
    kpart[((size_t)ck * HEADS + h) * HD + (t - 64)] = nacc;
}

// ---------------- reduce partials + temperature + softmax ---------------------
__global__ __launch_bounds__(64)
void attn_softmax(const float* __restrict__ Spart, const float* __restrict__ qpart,
                  const float* __restrict__ kpart, const float* __restrict__ log_temp,
                  float* __restrict__ attn) {
  const int h = blockIdx.x;
  const int c = threadIdx.x;
  __shared__ float kns[HD];
  const int cc = (c < HD) ? c : 0;
  float qs = 0.f, ks = 0.f;
  for (int ck = 0; ck < NCHUNK; ck++) {
    qs += qpart[((size_t)ck * HEADS + h) * HD + cc];
    ks += kpart[((size_t)ck * HEADS + h) * HD + cc];
  }
  float qn = fmaxf(sqrtf(qs), 1e-12f);
  if (c < HD) kns[c] = fmaxf(sqrtf(ks), 1e-12f);
  __syncthreads();
  if (c >= HD) return;
  float lt = log_temp[h];
  float temp = (lt > 20.f ? lt : log1pf(expf(lt))) + 1e-6f;
  float lg[HD];
#pragma unroll
  for (int d = 0; d < HD; d++) lg[d] = 0.f;
  for (int ck = 0; ck < NCHUNK; ck++) {
    const float* Sp = Spart + (((size_t)ck * HEADS + h) * HD + c) * HD;
#pragma unroll
    for (int d = 0; d < HD; d++) lg[d] += Sp[d];
  }
  float mx = -1e30f;
#pragma unroll
  for (int d = 0; d < HD; d++) {
    lg[d] = lg[d] / (qn * kns[d]) * temp;
    mx = fmaxf(mx, lg[d]);
  }
  float sum = 0.f;
#pragma unroll
  for (int d = 0; d < HD; d++) {
    lg[d] = expf(lg[d] - mx);
    sum += lg[d];
  }
  float inv = 1.f / sum;
#pragma unroll
  for (int d = 0; d < HD; d++) attn[((size_t)h * HD + c) * HD + d] = lg[d] * inv;
}

// ---------------- fold proj_w through block-diagonal attn ---------------------
__global__ __launch_bounds__(256)
void fuse_proj(const float* __restrict__ proj_w, const float* __restrict__ attn,
               float* __restrict__ Mmat) {
  int idx = blockIdx.x * 256 + threadIdx.x;
  int o = idx / CDIM, j = idx % CDIM;
  int h = j / HD, d = j % HD;
  float s = 0.f;
#pragma unroll 8
  for (int c = 0; c < HD; c++)
    s = fmaf(proj_w[(size_t)o * CDIM + h * HD + c],
             attn[((size_t)h * HD + c) * HD + d], s);
  Mmat[idx] = s;
}

extern "C" void kernel_launch(void* const* d_in, const int* in_sizes, int n_in,
                              void* d_out, int out_size, void* d_ws, size_t ws_size,
                              hipStream_t stream) {
  const float* x = (const float*)d_in[0];       // (2, 384, 256, 256)
  const float* qkv_w = (const float*)d_in[1];   // (1152, 384)
  const float* dw_w = (const float*)d_in[2];    // (1152, 1, 3, 3)
  const float* proj_w = (const float*)d_in[3];  // (384, 384)
  const float* log_t = (const float*)d_in[4];   // (8,)
  float* out = (float*)d_out;

  float* ws = (float*)d_ws;
  const size_t C3HW = (size_t)C3 * HW;
  float* qkv = ws;                                          // 302 MB
  float* qkvdw = qkv + C3HW;                                // 302 MB
  float* Spart = qkvdw + C3HW;                              // 9.4 MB
  float* qpart = Spart + (size_t)NCHUNK * HEADS * HD * HD;
  float* kpart = qpart + (size_t)NCHUNK * HEADS * HD;
  float* attn = kpart + (size_t)NCHUNK * HEADS * HD;
  float* Mmat = attn + (size_t)HEADS * HD * HD;
  u16* qkvw_h = (u16*)(Mmat + (size_t)CDIM * CDIM);         // +1.77 MB (persistent)
  u16* qkvw_l = qkvw_h + (size_t)C3 * CDIM;
  // Mh/Ml alias the head of Spart: Spart is dead after attn_softmax; Mh/Ml live
  // only fuse_proj+split_cvt -> epilogue GEMM; next Spart write is the NEXT
  // batch's gram48, strictly after the epilogue GEMM. Lifetimes disjoint.
  u16* Mh = (u16*)Spart;
  u16* Ml = Mh + (size_t)CDIM * CDIM;
  // aliases into the two big buffers (lifetimes disjoint):
  u16* xT_h = (u16*)qkvdw;                                  // dead after GEMM1
  u16* xT_l = xT_h + (size_t)HW * CDIM;
  u16* vT_h = (u16*)qkv;                                    // qkv dead after dwconv
  u16* vT_l = vT_h + (size_t)HW * CDIM;

  split_cvt<<<dim3((C3 * CDIM + 255) / 256), 256, 0, stream>>>(qkv_w, qkvw_h, qkvw_l,
                                                               C3 * CDIM);
  for (int b = 0; b < 2; b++) {
    const float* xb = x + (size_t)b * CDIM * HW;
    float* outb = out + (size_t)b * CDIM * HW;
    // 1) xT (bf16 hi/lo, [n][c]) into qkvdw region
    transpose_cvt<<<dim3(HW / 64, CDIM / 64), 256, 0, stream>>>(xb, xT_h, xT_l);
    // 2) qkv = qkv_w @ x  via MFMA (1-D grid, XCD-locality swizzle)
    mfma_gemm_split<<<dim3((C3 / 128) * (HW / 128)), 256, 0, stream>>>(
        qkvw_h, qkvw_l, xT_h, xT_l, qkv, HW, CDIM, C3 / 128);
    // 3) depthwise 3x3 (overwrites xT region — xT is dead)
    dwconv3x3<<<dim3(HGT / 4, C3), 256, 0, stream>>>(qkv, dw_w, qkvdw);
    // 4) gram + norms, 5) softmax, 6) proj fold + split
    gram48<<<dim3(NCHUNK, HEADS), 256, 0, stream>>>(qkvdw, Spart, qpart, kpart);
    attn_softmax<<<dim3(HEADS), 64, 0, stream>>>(Spart, qpart, kpart, log_t, attn);
    fuse_proj<<<dim3(CDIM * CDIM / 256), 256, 0, stream>>>(proj_w, attn, Mmat);
    split_cvt<<<dim3(CDIM * CDIM / 256), 256, 0, stream>>>(Mmat, Mh, Ml, CDIM * CDIM);
    // 7) vT (bf16 hi/lo) into qkv region (qkv dead after dwconv)
    transpose_cvt<<<dim3(HW / 64, CDIM / 64), 256, 0, stream>>>(
        qkvdw + (size_t)2 * CDIM * HW, vT_h, vT_l);
    // 8) out = Mmat @ v via MFMA (1-D grid, XCD-locality swizzle)
    mfma_gemm_split<<<dim3((CDIM / 128) * (HW / 128)), 256, 0, stream>>>(
        Mh, Ml, vT_h, vT_l, outb, HW, CDIM, CDIM / 128);
  }
}

// Round 13
// 1763.329 us; speedup vs baseline: 1.5689x; 1.0091x over previous
//
#include <hip/hip_runtime.h>
#include <cstdint>
#include <cstddef>

#define HW 65536
#define HGT 256
#define WID 256
#define CDIM 384
#define C3 1152
#define HEADS 8
#define HD 48
#define NCHUNK 128
#define CHUNK (HW / NCHUNK)  // 512

typedef unsigned short u16;
typedef __attribute__((ext_vector_type(8))) short short8;    // 8 bf16 (4 VGPRs)
typedef __attribute__((ext_vector_type(16))) float f32x16;   // 32x32 MFMA C/D
typedef __attribute__((ext_vector_type(4))) u16 us4;

__device__ __forceinline__ u16 f2bf_rn(float f) {
  uint32_t u = __float_as_uint(f);
  return (u16)((u + 0x7FFFu + ((u >> 16) & 1u)) >> 16);
}
__device__ __forceinline__ float bf2f(u16 s) {
  return __uint_as_float((uint32_t)s << 16);
}

// async global->LDS, 16B/lane; LDS dest = wave-uniform base + lane*16 (HW rule)
__device__ __forceinline__ void stage16(const void* g, void* lds_wave_base) {
  __builtin_amdgcn_global_load_lds(
      (const __attribute__((address_space(1))) void*)g,
      (__attribute__((address_space(3))) void*)lds_wave_base, 16, 0, 0);
}

// ------------- split-bf16 MFMA GEMM: C[M,N]fp32 = (Ah+Al)[M,K] @ (Bh+Bl)^T ----
// A row-major [M][K] bf16; B given TRANSPOSED: [N][K] bf16. K % 32 == 0.
// Tile 128x128, BK=32, 256 thr = 4 waves (2x2), wave tile 64x64.
// Round-10 counters: FETCH 92MB (~ideal), MfmaUtil 36.8% = m97-structure ceiling
// at 16x16x32. This round: 32x32x16 MFMA (2x2 frags/wave, 2 k-substeps) — ~15%
// better per-FLOP rate (m119: 2495 vs 2176 TF), same LDS traffic and staging.
// 1-D grid with XCD-locality swizzle (round-10 verified: 740->92MB fetch).
__global__ __launch_bounds__(256)
void mfma_gemm_split(const u16* __restrict__ Ah, const u16* __restrict__ Al,
                     const u16* __restrict__ Bh, const u16* __restrict__ Bl,
                     float* __restrict__ C, int N, int K, int m_tiles) {
  __shared__ u16 sm[4][4096];  // [0]=Ah [1]=Al [2]=Bh [3]=Bl ; slot=(row, chunk)
  const int t = threadIdx.x;
  const int wid = t >> 6, lane = t & 63;
  // XCD swizzle decode (bijective: gridDim.x = 8 * per_xcd; per_xcd = npx*m_tiles)
  const int w = blockIdx.x;
  const int xcd = w & 7;
  const int slot = w >> 3;
  const int npx = (int)(gridDim.x >> 3) / m_tiles;  // n-panels per XCD
  const int m0 = (slot % m_tiles) * 128;
  const int n0 = (xcd * npx + slot / m_tiles) * 128;
  const int wm = (wid >> 1) * 64, wn = (wid & 1) * 64;

  f32x16 acc[2][2];
#pragma unroll
  for (int i = 0; i < 2; i++)
#pragma unroll
    for (int j = 0; j < 2; j++)
#pragma unroll
      for (int r = 0; r < 16; r++) acc[i][j][r] = 0.f;

  for (int k0 = 0; k0 < K; k0 += 32) {
    // ---- stage: 512 slots/buffer; wave stages 64-slot runs (linear LDS dest)
    // chunk-XOR swizzle (row>>1)&3 applied on GLOBAL source; LDS stays linear.
#pragma unroll
    for (int u = 0; u < 2; u++) {
      const int s = u * 256 + wid * 64 + lane;
      const int row = s >> 2;
      const int cd = (s & 3) ^ ((row >> 1) & 3);     // pre-swizzled global chunk
      const size_t offA = (size_t)(m0 + row) * K + k0 + cd * 8;
      const size_t offB = (size_t)(n0 + row) * K + k0 + cd * 8;
      const int lb = (u * 256 + wid * 64) * 8;       // ushort offset of wave base
      stage16(Ah + offA, &sm[0][lb]);
      stage16(Al + offA, &sm[1][lb]);
      stage16(Bh + offB, &sm[2][lb]);
      stage16(Bl + offB, &sm[3][lb]);
    }
    __syncthreads();  // compiler drains vmcnt(0) before barrier

    // 32x32x16 fragments: lane holds row/col = lane&31, k = (lane>>5)*8 + [0..8)
    // within k-substep ks (k = ks*16..ks*16+15): logical chunk = ks*2 + (lane>>5)
    short8 ah[2][2], al[2][2], bh[2][2], bl[2][2];   // [f][ks]
#pragma unroll
    for (int f = 0; f < 2; f++)
#pragma unroll
      for (int ks = 0; ks < 2; ks++) {
        const int ra = wm + f * 32 + (lane & 31);
        const int ca = (ks * 2 + (lane >> 5)) ^ ((ra >> 1) & 3);
        const int oa = ra * 32 + ca * 8;
        ah[f][ks] = *(const short8*)&sm[0][oa];
        al[f][ks] = *(const short8*)&sm[1][oa];
        const int rb = wn + f * 32 + (lane & 31);
        const int cb = (ks * 2 + (lane >> 5)) ^ ((rb >> 1) & 3);
        const int ob = rb * 32 + cb * 8;
        bh[f][ks] = *(const short8*)&sm[2][ob];
        bl[f][ks] = *(const short8*)&sm[3][ob];
      }
#pragma unroll
    for (int ks = 0; ks < 2; ks++)
#pragma unroll
      for (int i = 0; i < 2; i++)
#pragma unroll
        for (int j = 0; j < 2; j++) {
          acc[i][j] = __builtin_amdgcn_mfma_f32_32x32x16_bf16(ah[i][ks], bh[j][ks], acc[i][j], 0, 0, 0);
          acc[i][j] = __builtin_amdgcn_mfma_f32_32x32x16_bf16(ah[i][ks], bl[j][ks], acc[i][j], 0, 0, 0);
          acc[i][j] = __builtin_amdgcn_mfma_f32_32x32x16_bf16(al[i][ks], bh[j][ks], acc[i][j], 0, 0, 0);
        }
    __syncthreads();
  }
  // epilogue: 32x32 C/D layout col=lane&31, row=(reg&3)+8*(reg>>2)+4*(lane>>5)
  // [m74/m101-verified]
  float* Cb = C + (size_t)(m0 + wm) * N + n0 + wn;
#pragma unroll
  for (int i = 0; i < 2; i++)
#pragma unroll
    for (int j = 0; j < 2; j++) {
      const int cc = j * 32 + (lane & 31);
#pragma unroll
      for (int reg = 0; reg < 16; reg++) {
        const int rr = i * 32 + (reg & 3) + 8 * (reg >> 2) + 4 * (lane >> 5);
        Cb[(size_t)rr * N + cc] = acc[i][j][reg];
      }
    }
}

// ------------- transpose + split-convert: in[384][HW] f32 -> out[HW][384] bf16 --
__global__ __launch_bounds__(256)
void transpose_cvt(const float* __restrict__ in, u16* __restrict__ hi,
                   u16* __restrict__ lo) {
  __shared__ float tbuf[64][65];
  const int n0 = blockIdx.x * 64, c0 = blockIdx.y * 64;
  const int tx = threadIdx.x & 63, ty = threadIdx.x >> 6;
#pragma unroll
  for (int c = ty; c < 64; c += 4)
    tbuf[tx][c] = in[(size_t)(c0 + c) * HW + n0 + tx];
  __syncthreads();
  const int cq = (threadIdx.x & 15) << 2;
  const int nb = threadIdx.x >> 4;
#pragma unroll
  for (int p = 0; p < 4; p++) {
    const int n = p * 16 + nb;
    us4 h, l;
#pragma unroll
    for (int i = 0; i < 4; i++) {
      float f = tbuf[n][cq + i];
      u16 hb = f2bf_rn(f);
      h[i] = hb;
      l[i] = f2bf_rn(f - bf2f(hb));
    }
    *(us4*)&hi[(size_t)(n0 + n) * CDIM + c0 + cq] = h;
    *(us4*)&lo[(size_t)(n0 + n) * CDIM + c0 + cq] = l;
  }
}

// ------------- elementwise split-convert (weights / Mmat) ---------------------
__global__ __launch_bounds__(256)
void split_cvt(const float* __restrict__ in, u16* __restrict__ hi,
               u16* __restrict__ lo, int n) {
  int i = blockIdx.x * 256 + threadIdx.x;
  if (i < n) {
    float f = in[i];
    u16 hb = f2bf_rn(f);
    hi[i] = hb;
    lo[i] = f2bf_rn(f - bf2f(hb));
  }
}

// ---------------- depthwise 3x3, pad 1 (cross-correlation) --------------------
__global__ __launch_bounds__(256)
void dwconv3x3(const float* __restrict__ in, const float* __restrict__ wgt,
               float* __restrict__ out) {
  const int ch = blockIdx.y;
  const int y0 = blockIdx.x * 4;
  const int t = threadIdx.x;
  __shared__ float rows[6][264];
  const float* inc = in + (size_t)ch * HW;
  float w9[9];
#pragma unroll
  for (int k = 0; k < 9; k++) w9[k] = wgt[ch * 9 + k];
  if (t < 6) {
    rows[t][0] = 0.f;
    rows[t][WID + 1] = 0.f;
  }
  for (int i = t; i < 6 * WID; i += 256) {
    int r = i >> 8;
    int x = i & 255;
    int y = y0 - 1 + r;
    rows[r][1 + x] = (y >= 0 && y < HGT) ? inc[(size_t)y * WID + x] : 0.f;
  }
  __syncthreads();
  const int x = t;
#pragma unroll
  for (int r = 0; r < 4; r++) {
    float s = 0.f;
#pragma unroll
    for (int ky = 0; ky < 3; ky++)
#pragma unroll
      for (int kx = 0; kx < 3; kx++)
        s = fmaf(w9[ky * 3 + kx], rows[r + ky][x + kx], s);
    out[(size_t)ch * HW + (size_t)(y0 + r) * WID + x] = s;
  }
}

// ---------------- gram matrices + squared norms (split-K partials) ------------
__global__ __launch_bounds__(256)
void gram48(const float* __restrict__ qkvdw, float* __restrict__ Spart,
            float* __restrict__ qpart, float* __restrict__ kpart) {
  const int ck = blockIdx.x;
  const int h = blockIdx.y;
  const int t = threadIdx.x;
  const int ty = t >> 4, tx = t & 15;
  __shared__ float Qs[HD][33], Ks[HD][33];
  const float* qb = qkvdw + (size_t)(h * HD) * HW + ck * CHUNK;
  const float* kb = qkvdw + (size_t)(CDIM + h * HD) * HW + ck * CHUNK;
  float acc[3][3] = {{0, 0, 0}, {0, 0, 0}, {0, 0, 0}};
  float nacc = 0.f;
  for (int n0 = 0; n0 < CHUNK; n0 += 32) {
    __syncthreads();
    for (int i = t; i < HD * 32; i += 256) {
      int r = i >> 5, c = i & 31;
      Qs[r][c] = qb[(size_t)r * HW + n0 + c];
      Ks[r][c] = kb[(size_t)r * HW + n0 + c];
    }
    __syncthreads();
#pragma unroll 4
    for (int col = 0; col < 32; col++) {
      float qv[3], kv[3];
#pragma unroll
      for (int i = 0; i < 3; i++) qv[i] = Qs[ty * 3 + i][col];
#pragma unroll
      for (int j = 0; j < 3; j++) kv[j] = Ks[tx * 3 + j][col];
#pragma unroll
      for (int i = 0; i < 3; i++)
#pragma unroll
        for (int j = 0; j < 3; j++) acc[i][j] = fmaf(qv[i], kv[j], acc[i][j]);
    }
    if (t < HD) {
#pragma unroll 4
      for (int col = 0; col < 32; col++) nacc = fmaf(Qs[t][col], Qs[t][col], nacc);
    } else if (t >= 64 && t < 64 + HD) {
      int r = t - 64;
#pragma unroll 4
      for (int col = 0; col < 32; col++) nacc = fmaf(Ks[r][col], Ks[r][col], nacc);
    }
  }
  float* Sp = Spart + ((size_t)ck * HEADS + h) * HD * HD;
#pragma unroll
  for (int i = 0; i < 3; i++)
#pragma unroll
    for (int j = 0; j < 3; j++)
      Sp[(ty * 3 + i) * HD + tx * 3 + j] = acc[i][j];
  if (t < HD)
    qpart[((size_t)ck * HEADS + h) * HD + t] = nacc;
  else if (t >= 64 && t < 64 + HD)
    kpart[((size_t)ck * HEADS + h) * HD + (t - 64)] = nacc;
}

// ---------------- reduce partials + temperature + softmax ---------------------
__global__ __launch_bounds__(64)
void attn_softmax(const float* __restrict__ Spart, const float* __restrict__ qpart,
                  const float* __restrict__ kpart, const float* __restrict__ log_temp,
                  float* __restrict__ attn) {
  const int h = blockIdx.x;
  const int c = threadIdx.x;
  __shared__ float kns[HD];
  const int cc = (c < HD) ? c : 0;
  float qs = 0.f, ks = 0.f;
  for (int ck = 0; ck < NCHUNK; ck++) {
    qs += qpart[((size_t)ck * HEADS + h) * HD + cc];
    ks += kpart[((size_t)ck * HEADS + h) * HD + cc];
  }
  float qn = fmaxf(sqrtf(qs), 1e-12f);
  if (c < HD) kns[c] = fmaxf(sqrtf(ks), 1e-12f);
  __syncthreads();
  if (c >= HD) return;
  float lt = log_temp[h];
  float temp = (lt > 20.f ? lt : log1pf(expf(lt))) + 1e-6f;
  float lg[HD];
#pragma unroll
  for (int d = 0; d < HD; d++) lg[d] = 0.f;
  for (int ck = 0; ck < NCHUNK; ck++) {
    const float* Sp = Spart + (((size_t)ck * HEADS + h) * HD + c) * HD;
#pragma unroll
    for (int d = 0; d < HD; d++) lg[d] += Sp[d];
  }
  float mx = -1e30f;
#pragma unroll
  for (int d = 0; d < HD; d++) {
    lg[d] = lg[d] / (qn * kns[d]) * temp;
    mx = fmaxf(mx, lg[d]);
  }
  float sum = 0.f;
#pragma unroll
  for (int d = 0; d < HD; d++) {
    lg[d] = expf(lg[d] - mx);
    sum += lg[d];
  }
  float inv = 1.f / sum;
#pragma unroll
  for (int d = 0; d < HD; d++) attn[((size_t)h * HD + c) * HD + d] = lg[d] * inv;
}

// ---------------- fold proj_w through block-diagonal attn ---------------------
__global__ __launch_bounds__(256)
void fuse_proj(const float* __restrict__ proj_w, const float* __restrict__ attn,
               float* __restrict__ Mmat) {
  int idx = blockIdx.x * 256 + threadIdx.x;
  int o = idx / CDIM, j = idx % CDIM;
  int h = j / HD, d = j % HD;
  float s = 0.f;
#pragma unroll 8
  for (int c = 0; c < HD; c++)
    s = fmaf(proj_w[(size_t)o * CDIM + h * HD + c],
             attn[((size_t)h * HD + c) * HD + d], s);
  Mmat[idx] = s;
}

extern "C" void kernel_launch(void* const* d_in, const int* in_sizes, int n_in,
                              void* d_out, int out_size, void* d_ws, size_t ws_size,
                              hipStream_t stream) {
  const float* x = (const float*)d_in[0];       // (2, 384, 256, 256)
  const float* qkv_w = (const float*)d_in[1];   // (1152, 384)
  const float* dw_w = (const float*)d_in[2];    // (1152, 1, 3, 3)
  const float* proj_w = (const float*)d_in[3];  // (384, 384)
  const float* log_t = (const float*)d_in[4];   // (8,)
  float* out = (float*)d_out;

  float* ws = (float*)d_ws;
  const size_t C3HW = (size_t)C3 * HW;
  float* qkv = ws;                                          // 302 MB
  float* qkvdw = qkv + C3HW;                                // 302 MB
  float* Spart = qkvdw + C3HW;                              // 9.4 MB
  float* qpart = Spart + (size_t)NCHUNK * HEADS * HD * HD;
  float* kpart = qpart + (size_t)NCHUNK * HEADS * HD;
  float* attn = kpart + (size_t)NCHUNK * HEADS * HD;
  float* Mmat = attn + (size_t)HEADS * HD * HD;
  u16* qkvw_h = (u16*)(Mmat + (size_t)CDIM * CDIM);         // +1.77 MB (persistent)
  u16* qkvw_l = qkvw_h + (size_t)C3 * CDIM;
  // Mh/Ml alias the head of Spart: Spart is dead after attn_softmax; Mh/Ml live
  // only fuse_proj+split_cvt -> epilogue GEMM; next Spart write is the NEXT
  // batch's gram48, strictly after the epilogue GEMM. Lifetimes disjoint.
  u16* Mh = (u16*)Spart;
  u16* Ml = Mh + (size_t)CDIM * CDIM;
  // aliases into the two big buffers (lifetimes disjoint):
  u16* xT_h = (u16*)qkvdw;                                  // dead after GEMM1
  u16* xT_l = xT_h + (size_t)HW * CDIM;
  u16* vT_h = (u16*)qkv;                                    // qkv dead after dwconv
  u16* vT_l = vT_h + (size_t)HW * CDIM;

  split_cvt<<<dim3((C3 * CDIM + 255) / 256), 256, 0, stream>>>(qkv_w, qkvw_h, qkvw_l,
                                                               C3 * CDIM);
  for (int b = 0; b < 2; b++) {
    const float* xb = x + (size_t)b * CDIM * HW;
    float* outb = out + (size_t)b * CDIM * HW;
    // 1) xT (bf16 hi/lo, [n][c]) into qkvdw region
    transpose_cvt<<<dim3(HW / 64, CDIM / 64), 256, 0, stream>>>(xb, xT_h, xT_l);
    // 2) qkv = qkv_w @ x  via MFMA (1-D grid, XCD-locality swizzle)
    mfma_gemm_split<<<dim3((C3 / 128) * (HW / 128)), 256, 0, stream>>>(
        qkvw_h, qkvw_l, xT_h, xT_l, qkv, HW, CDIM, C3 / 128);
    // 3) depthwise 3x3 (overwrites xT region — xT is dead)
    dwconv3x3<<<dim3(HGT / 4, C3), 256, 0, stream>>>(qkv, dw_w, qkvdw);
    // 4) gram + norms, 5) softmax, 6) proj fold + split
    gram48<<<dim3(NCHUNK, HEADS), 256, 0, stream>>>(qkvdw, Spart, qpart, kpart);
    attn_softmax<<<dim3(HEADS), 64, 0, stream>>>(Spart, qpart, kpart, log_t, attn);
    fuse_proj<<<dim3(CDIM * CDIM / 256), 256, 0, stream>>>(proj_w, attn, Mmat);
    split_cvt<<<dim3(CDIM * CDIM / 256), 256, 0, stream>>>(Mmat, Mh, Ml, CDIM * CDIM);
    // 7) vT (bf16 hi/lo) into qkv region (qkv dead after dwconv)
    transpose_cvt<<<dim3(HW / 64, CDIM / 64), 256, 0, stream>>>(
        qkvdw + (size_t)2 * CDIM * HW, vT_h, vT_l);
    // 8) out = Mmat @ v via MFMA (1-D grid, XCD-locality swizzle)
    mfma_gemm_split<<<dim3((CDIM / 128) * (HW / 128)), 256, 0, stream>>>(
        Mh, Ml, vT_h, vT_l, outb, HW, CDIM, CDIM / 128);
  }
}

// Round 14
// 1714.219 us; speedup vs baseline: 1.6139x; 1.0286x over previous
//
#include <hip/hip_runtime.h>
#include <cstdint>
#include <cstddef>

#define HW 65536
#define HGT 256
#define WID 256
#define CDIM 384
#define C3 1152
#define HEADS 8
#define HD 48
#define NCHUNK 128
#define CHUNK (HW / NCHUNK)  // 512

typedef unsigned short u16;
typedef __attribute__((ext_vector_type(8))) short short8;    // 8 bf16 (4 VGPRs)
typedef __attribute__((ext_vector_type(16))) float f32x16;   // 32x32 MFMA C/D
typedef __attribute__((ext_vector_type(4))) u16 us4;

__device__ __forceinline__ u16 f2bf_rn(float f) {
  uint32_t u = __float_as_uint(f);
  return (u16)((u + 0x7FFFu + ((u >> 16) & 1u)) >> 16);
}
__device__ __forceinline__ float bf2f(u16 s) {
  return __uint_as_float((uint32_t)s << 16);
}

// async global->LDS, 16B/lane; LDS dest = wave-uniform base + lane*16 (HW rule)
__device__ __forceinline__ void stage16(const void* g, void* lds_wave_base) {
  __builtin_amdgcn_global_load_lds(
      (const __attribute__((address_space(1))) void*)g,
      (__attribute__((address_space(3))) void*)lds_wave_base, 16, 0, 0);
}

// ------- split-bf16 MFMA GEMM, fp32 B: C[M,N] = (Ah+Al)[M,K] @ B[K,N] --------
// A row-major [M][K] bf16 hi/lo (pre-split); B row-major [K][N] fp32 read
// DIRECTLY (n contiguous) — eliminates the separate transpose+split pass.
// Same staged bytes/elem (fp32 == bf16 hi+lo); hi/lo split done in-register
// in the 48% stall + idle-VALU headroom measured in round 13 (VALUBusy 14.5%).
// Tile 128x128, BK=32, 4 waves (2x2), wave tile 64x64, 32x32x16 MFMA.
// LDS 32KB: A 2x8KB (chunk-XOR swizzled via global source, rule #21),
// B 16KB linear fp32 (fragment read = 8x ds_read_b32, 2-way alias = free).
// 1-D grid + XCD-locality swizzle (round-10: FETCH 740->92MB). n_tiles%8==0.
__global__ __launch_bounds__(256)
void mfma_gemm_f32b(const u16* __restrict__ Ah, const u16* __restrict__ Al,
                    const float* __restrict__ B, float* __restrict__ C,
                    int N, int K, int m_tiles) {
  __shared__ u16 smA[2][4096];   // [0]=Ah [1]=Al ; slot=(row, chunk)
  __shared__ float smB[4096];    // [krow 0..31][ncol 0..127] linear
  const int t = threadIdx.x;
  const int wid = t >> 6, lane = t & 63;
  const int w = blockIdx.x;
  const int xcd = w & 7;
  const int slot = w >> 3;
  const int npx = (int)(gridDim.x >> 3) / m_tiles;  // n-panels per XCD
  const int m0 = (slot % m_tiles) * 128;
  const int n0 = (xcd * npx + slot / m_tiles) * 128;
  const int wm = (wid >> 1) * 64, wn = (wid & 1) * 64;

  f32x16 acc[2][2];
#pragma unroll
  for (int i = 0; i < 2; i++)
#pragma unroll
    for (int j = 0; j < 2; j++)
#pragma unroll
      for (int r = 0; r < 16; r++) acc[i][j][r] = 0.f;

  for (int k0 = 0; k0 < K; k0 += 32) {
    // ---- stage A: 512 slots/buffer (128 rows x 4 chunks of 8 u16)
#pragma unroll
    for (int u = 0; u < 2; u++) {
      const int s = u * 256 + wid * 64 + lane;
      const int row = s >> 2;
      const int cd = (s & 3) ^ ((row >> 1) & 3);     // pre-swizzled global chunk
      const size_t offA = (size_t)(m0 + row) * K + k0 + cd * 8;
      const int lb = (u * 256 + wid * 64) * 8;
      stage16(Ah + offA, &smA[0][lb]);
      stage16(Al + offA, &smA[1][lb]);
    }
    // ---- stage B: 1024 slots (32 k-rows x 32 chunks of 4 floats), linear
#pragma unroll
    for (int u = 0; u < 4; u++) {
      const int s = u * 256 + wid * 64 + lane;
      const int row = s >> 5;                        // k-row
      const int c5 = s & 31;                         // 16B chunk along n
      const size_t offB = (size_t)(k0 + row) * (size_t)N + n0 + c5 * 4;
      const int lb = (u * 256 + wid * 64) * 4;       // float offset of wave base
      stage16(B + offB, &smB[lb]);
    }
    __syncthreads();  // compiler drains vmcnt(0) before barrier

    // A fragments (32x32x16): row = lane&31, k = (lane>>5)*8 + [0..8)
    short8 ah[2][2], al[2][2];
#pragma unroll
    for (int f = 0; f < 2; f++)
#pragma unroll
      for (int ks = 0; ks < 2; ks++) {
        const int ra = wm + f * 32 + (lane & 31);
        const int ca = (ks * 2 + (lane >> 5)) ^ ((ra >> 1) & 3);
        const int oa = ra * 32 + ca * 8;
        ah[f][ks] = *(const short8*)&smA[0][oa];
        al[f][ks] = *(const short8*)&smA[1][oa];
      }
    // B fragments: col = lane&31, k strided reads from fp32 + in-reg hi/lo split
    // (hi = truncate -> residual exact; lo = RN(residual): 2^-17 rel overall)
    short8 bh[2][2], bl[2][2];
#pragma unroll
    for (int f = 0; f < 2; f++)
#pragma unroll
      for (int ks = 0; ks < 2; ks++) {
        const int ncol = wn + f * 32 + (lane & 31);
        const int kb = ks * 16 + (lane >> 5) * 8;
#pragma unroll
        for (int e = 0; e < 8; e++) {
          const float v = smB[(kb + e) * 128 + ncol];
          const uint32_t uv = __float_as_uint(v);
          const u16 h = (u16)(uv >> 16);             // truncated hi
          const u16 l = f2bf_rn(v - bf2f(h));        // RN lo of exact residual
          bh[f][ks][e] = (short)h;
          bl[f][ks][e] = (short)l;
        }
      }
#pragma unroll
    for (int ks = 0; ks < 2; ks++)
#pragma unroll
      for (int i = 0; i < 2; i++)
#pragma unroll
        for (int j = 0; j < 2; j++) {
          acc[i][j] = __builtin_amdgcn_mfma_f32_32x32x16_bf16(ah[i][ks], bh[j][ks], acc[i][j], 0, 0, 0);
          acc[i][j] = __builtin_amdgcn_mfma_f32_32x32x16_bf16(ah[i][ks], bl[j][ks], acc[i][j], 0, 0, 0);
          acc[i][j] = __builtin_amdgcn_mfma_f32_32x32x16_bf16(al[i][ks], bh[j][ks], acc[i][j], 0, 0, 0);
        }
    __syncthreads();
  }
  // epilogue: 32x32 C/D layout col=lane&31, row=(reg&3)+8*(reg>>2)+4*(lane>>5)
  float* Cb = C + (size_t)(m0 + wm) * N + n0 + wn;
#pragma unroll
  for (int i = 0; i < 2; i++)
#pragma unroll
    for (int j = 0; j < 2; j++) {
      const int cc = j * 32 + (lane & 31);
#pragma unroll
      for (int reg = 0; reg < 16; reg++) {
        const int rr = i * 32 + (reg & 3) + 8 * (reg >> 2) + 4 * (lane >> 5);
        Cb[(size_t)rr * N + cc] = acc[i][j][reg];
      }
    }
}

// ------------- elementwise split-convert (weights / Mmat) ---------------------
__global__ __launch_bounds__(256)
void split_cvt(const float* __restrict__ in, u16* __restrict__ hi,
               u16* __restrict__ lo, int n) {
  int i = blockIdx.x * 256 + threadIdx.x;
  if (i < n) {
    float f = in[i];
    u16 hb = f2bf_rn(f);
    hi[i] = hb;
    lo[i] = f2bf_rn(f - bf2f(hb));
  }
}

// ---------------- depthwise 3x3, pad 1 (cross-correlation) --------------------
__global__ __launch_bounds__(256)
void dwconv3x3(const float* __restrict__ in, const float* __restrict__ wgt,
               float* __restrict__ out) {
  const int ch = blockIdx.y;
  const int y0 = blockIdx.x * 4;
  const int t = threadIdx.x;
  __shared__ float rows[6][264];
  const float* inc = in + (size_t)ch * HW;
  float w9[9];
#pragma unroll
  for (int k = 0; k < 9; k++) w9[k] = wgt[ch * 9 + k];
  if (t < 6) {
    rows[t][0] = 0.f;
    rows[t][WID + 1] = 0.f;
  }
  for (int i = t; i < 6 * WID; i += 256) {
    int r = i >> 8;
    int x = i & 255;
    int y = y0 - 1 + r;
    rows[r][1 + x] = (y >= 0 && y < HGT) ? inc[(size_t)y * WID + x] : 0.f;
  }
  __syncthreads();
  const int x = t;
#pragma unroll
  for (int r = 0; r < 4; r++) {
    float s = 0.f;
#pragma unroll
    for (int ky = 0; ky < 3; ky++)
#pragma unroll
      for (int kx = 0; kx < 3; kx++)
        s = fmaf(w9[ky * 3 + kx], rows[r + ky][x + kx], s);
    out[(size_t)ch * HW + (size_t)(y0 + r) * WID + x] = s;
  }
}

// ---------------- gram matrices + squared norms (split-K partials) ------------
__global__ __launch_bounds__(256)
void gram48(const float* __restrict__ qkvdw, float* __restrict__ Spart,
            float* __restrict__ qpart, float* __restrict__ kpart) {
  const int ck = blockIdx.x;
  const int h = blockIdx.y;
  const int t = threadIdx.x;
  const int ty = t >> 4, tx = t & 15;
  __shared__ float Qs[HD][33], Ks[HD][33];
  const float* qb = qkvdw + (size_t)(h * HD) * HW + ck * CHUNK;
  const float* kb = qkvdw + (size_t)(CDIM + h * HD) * HW + ck * CHUNK;
  float acc[3][3] = {{0, 0, 0}, {0, 0, 0}, {0, 0, 0}};
  float nacc = 0.f;
  for (int n0 = 0; n0 < CHUNK; n0 += 32) {
    __syncthreads();
    for (int i = t; i < HD * 32; i += 256) {
      int r = i >> 5, c = i & 31;
      Qs[r][c] = qb[(size_t)r * HW + n0 + c];
      Ks[r][c] = kb[(size_t)r * HW + n0 + c];
    }
    __syncthreads();
#pragma unroll 4
    for (int col = 0; col < 32; col++) {
      float qv[3], kv[3];
#pragma unroll
      for (int i = 0; i < 3; i++) qv[i] = Qs[ty * 3 + i][col];
#pragma unroll
      for (int j = 0; j < 3; j++) kv[j] = Ks[tx * 3 + j][col];
#pragma unroll
      for (int i = 0; i < 3; i++)
#pragma unroll
        for (int j = 0; j < 3; j++) acc[i][j] = fmaf(qv[i], kv[j], acc[i][j]);
    }
    if (t < HD) {
#pragma unroll 4
      for (int col = 0; col < 32; col++) nacc = fmaf(Qs[t][col], Qs[t][col], nacc);
    } else if (t >= 64 && t < 64 + HD) {
      int r = t - 64;
#pragma unroll 4
      for (int col = 0; col < 32; col++) nacc = fmaf(Ks[r][col], Ks[r][col], nacc);
    }
  }
  float* Sp = Spart + ((size_t)ck * HEADS + h) * HD * HD;
#pragma unroll
  for (int i = 0; i < 3; i++)
#pragma unroll
    for (int j = 0; j < 3; j++)
      Sp[(ty * 3 + i) * HD + tx * 3 + j] = acc[i][j];
  if (t < HD)
    qpart[((size_t)ck * HEADS + h) * HD + t] = nacc;
  else if (t >= 64 && t < 64 + HD)
    kpart[((size_t)ck * HEADS + h) * HD + (t - 64)] = nacc;
}

// ---------------- reduce partials + temperature + softmax ---------------------
__global__ __launch_bounds__(64)
void attn_softmax(const float* __restrict__ Spart, const float* __restrict__ qpart,
                  const float* __restrict__ kpart, const float* __restrict__ log_temp,
                  float* __restrict__ attn) {
  const int h = blockIdx.x;
  const int c = threadIdx.x;
  __shared__ float kns[HD];
  const int cc = (c < HD) ? c : 0;
  float qs = 0.f, ks = 0.f;
  for (int ck = 0; ck < NCHUNK; ck++) {
    qs += qpart[((size_t)ck * HEADS + h) * HD + cc];
    ks += kpart[((size_t)ck * HEADS + h) * HD + cc];
  }
  float qn = fmaxf(sqrtf(qs), 1e-12f);
  if (c < HD) kns[c] = fmaxf(sqrtf(ks), 1e-12f);
  __syncthreads();
  if (c >= HD) return;
  float lt = log_temp[h];
  float temp = (lt > 20.f ? lt : log1pf(expf(lt))) + 1e-6f;
  float lg[HD];
#pragma unroll
  for (int d = 0; d < HD; d++) lg[d] = 0.f;
  for (int ck = 0; ck < NCHUNK; ck++) {
    const float* Sp = Spart + (((size_t)ck * HEADS + h) * HD + c) * HD;
#pragma unroll
    for (int d = 0; d < HD; d++) lg[d] += Sp[d];
  }
  float mx = -1e30f;
#pragma unroll
  for (int d = 0; d < HD; d++) {
    lg[d] = lg[d] / (qn * kns[d]) * temp;
    mx = fmaxf(mx, lg[d]);
  }
  float sum = 0.f;
#pragma unroll
  for (int d = 0; d < HD; d++) {
    lg[d] = expf(lg[d] - mx);
    sum += lg[d];
  }
  float inv = 1.f / sum;
#pragma unroll
  for (int d = 0; d < HD; d++) attn[((size_t)h * HD + c) * HD + d] = lg[d] * inv;
}

// ---------------- fold proj_w through block-diagonal attn ---------------------
__global__ __launch_bounds__(256)
void fuse_proj(const float* __restrict__ proj_w, const float* __restrict__ attn,
               float* __restrict__ Mmat) {
  int idx = blockIdx.x * 256 + threadIdx.x;
  int o = idx / CDIM, j = idx % CDIM;
  int h = j / HD, d = j % HD;
  float s = 0.f;
#pragma unroll 8
  for (int c = 0; c < HD; c++)
    s = fmaf(proj_w[(size_t)o * CDIM + h * HD + c],
             attn[((size_t)h * HD + c) * HD + d], s);
  Mmat[idx] = s;
}

extern "C" void kernel_launch(void* const* d_in, const int* in_sizes, int n_in,
                              void* d_out, int out_size, void* d_ws, size_t ws_size,
                              hipStream_t stream) {
  const float* x = (const float*)d_in[0];       // (2, 384, 256, 256)
  const float* qkv_w = (const float*)d_in[1];   // (1152, 384)
  const float* dw_w = (const float*)d_in[2];    // (1152, 1, 3, 3)
  const float* proj_w = (const float*)d_in[3];  // (384, 384)
  const float* log_t = (const float*)d_in[4];   // (8,)
  float* out = (float*)d_out;

  float* ws = (float*)d_ws;
  const size_t C3HW = (size_t)C3 * HW;
  float* qkv = ws;                                          // 302 MB
  float* qkvdw = qkv + C3HW;                                // 302 MB
  float* Spart = qkvdw + C3HW;                              // 9.4 MB
  float* qpart = Spart + (size_t)NCHUNK * HEADS * HD * HD;
  float* kpart = qpart + (size_t)NCHUNK * HEADS * HD;
  float* attn = kpart + (size_t)NCHUNK * HEADS * HD;
  float* Mmat = attn + (size_t)HEADS * HD * HD;
  u16* qkvw_h = (u16*)(Mmat + (size_t)CDIM * CDIM);         // 1.77 MB persistent
  u16* qkvw_l = qkvw_h + (size_t)C3 * CDIM;
  u16* Mh = qkvw_l + (size_t)C3 * CDIM;                     // 0.59 MB
  u16* Ml = Mh + (size_t)CDIM * CDIM;

  split_cvt<<<dim3((C3 * CDIM + 255) / 256), 256, 0, stream>>>(qkv_w, qkvw_h, qkvw_l,
                                                               C3 * CDIM);
  for (int b = 0; b < 2; b++) {
    const float* xb = x + (size_t)b * CDIM * HW;
    float* outb = out + (size_t)b * CDIM * HW;
    // 1) qkv = qkv_w @ x — B = x read DIRECTLY as fp32 (no transpose pass)
    mfma_gemm_f32b<<<dim3((C3 / 128) * (HW / 128)), 256, 0, stream>>>(
        qkvw_h, qkvw_l, xb, qkv, HW, CDIM, C3 / 128);
    // 2) depthwise 3x3
    dwconv3x3<<<dim3(HGT / 4, C3), 256, 0, stream>>>(qkv, dw_w, qkvdw);
    // 3) gram + norms, 4) softmax, 5) proj fold + split (tiny)
    gram48<<<dim3(NCHUNK, HEADS), 256, 0, stream>>>(qkvdw, Spart, qpart, kpart);
    attn_softmax<<<dim3(HEADS), 64, 0, stream>>>(Spart, qpart, kpart, log_t, attn);
    fuse_proj<<<dim3(CDIM * CDIM / 256), 256, 0, stream>>>(proj_w, attn, Mmat);
    split_cvt<<<dim3(CDIM * CDIM / 256), 256, 0, stream>>>(Mmat, Mh, Ml, CDIM * CDIM);
    // 6) out = Mmat @ v — B = v (dwconv output) read DIRECTLY as fp32
    mfma_gemm_f32b<<<dim3((CDIM / 128) * (HW / 128)), 256, 0, stream>>>(
        Mh, Ml, qkvdw + (size_t)2 * CDIM * HW, outb, HW, CDIM, CDIM / 128);
  }
}